// Round 16
// baseline (713.957 us; speedup 1.0000x reference)
//
#include <hip/hip_runtime.h>
#include <hip/hip_bf16.h>
#include <stdint.h>

#define B_  32
#define L_  2048   // L1 == L2
#define D_  1024   // D1 == D2

typedef __attribute__((ext_vector_type(8))) _Float16 f16x8;
typedef __attribute__((ext_vector_type(4))) float f32x4;

// ---------- helpers ----------
__device__ __forceinline__ unsigned enc_f(float x) {
  unsigned u = __float_as_uint(x);
  return (u & 0x80000000u) ? ~u : (u | 0x80000000u);
}
__device__ __forceinline__ float dec_f(unsigned e) {
  unsigned u = (e & 0x80000000u) ? (e ^ 0x80000000u) : ~e;
  return __uint_as_float(u);
}
__device__ __forceinline__ ushort f16_bits(float x) {
  _Float16 h = (_Float16)x;               // RNE convert
  return __builtin_bit_cast(ushort, h);
}
__device__ __forceinline__ void split_f16(float x, ushort& h, ushort& l) {
  _Float16 hf = (_Float16)x;
  float r = x - (float)hf;
  h = __builtin_bit_cast(ushort, hf);
  l = __builtin_bit_cast(ushort, (_Float16)r);
}

// async global->LDS, 16B per lane; LDS dest wave-uniform, lane*16 placement.
__device__ __forceinline__ void gl_lds16(const ushort* g, ushort* l) {
  using gas_t = const __attribute__((address_space(1))) uint32_t*;
  using las_t = __attribute__((address_space(3))) uint32_t*;
  __builtin_amdgcn_global_load_lds((gas_t)(uintptr_t)g,
                                   (las_t)(unsigned)(uintptr_t)l, 16, 0, 0);
}

// ---------- decompose fp32 -> f16 hi plane only ----------
__global__ void dec1_k(const float4* __restrict__ x, uint2* __restrict__ h, int n4) {
  int i = blockIdx.x * blockDim.x + threadIdx.x;
  const int stride = gridDim.x * blockDim.x;
  for (; i < n4; i += stride) {
    float4 v = x[i];
    uint2 hw;
    hw.x = (unsigned)f16_bits(v.x) | ((unsigned)f16_bits(v.y) << 16);
    hw.y = (unsigned)f16_bits(v.z) | ((unsigned)f16_bits(v.w) << 16);
    h[i] = hw;
  }
}

// ---------- transpose + decompose U (scaled by 2048 to keep U_lo in f16 normal range) ----------
__global__ void transdec_k(const float* __restrict__ U,
                           ushort* __restrict__ UTh, ushort* __restrict__ UTl) {
  __shared__ float t[32][33];
  const int tx = threadIdx.x, ty = threadIdx.y;
  const int e0 = blockIdx.x * 32, d0 = blockIdx.y * 32;
#pragma unroll
  for (int r = 0; r < 4; ++r)
    t[ty + r * 8][tx] = U[(size_t)(d0 + ty + r * 8) * D_ + e0 + tx];
  __syncthreads();
#pragma unroll
  for (int r = 0; r < 4; ++r) {
    int e = ty + r * 8;
    ushort h, l;
    split_f16(t[tx][e] * 2048.0f, h, l);
    UTh[(size_t)(e0 + e) * D_ + d0 + tx] = h;
    UTl[(size_t)(e0 + e) * D_ + d0 + tx] = l;
  }
}

// ============ 256x256 tile GEMM cores: 8 waves (2x4), f16 ============
struct CoreCtx {
  int w, lane, ln, kq, wm, wn, ko;
  size_t soA;   // BK=32 staging offset (gemm1)
};

__device__ __forceinline__ CoreCtx make_ctx() {
  CoreCtx c;
  const int tid = threadIdx.x;
  c.w = tid >> 6; c.lane = tid & 63;
  c.ln = c.lane & 15; c.kq = c.lane >> 4;
  c.wm = c.w >> 2; c.wn = c.w & 3;
  c.ko = (c.kq ^ ((c.ln >> 1) & 3)) * 8;
  const int srow = c.lane >> 2;
  const int sslot = (c.lane & 3) ^ ((c.lane >> 3) & 3);
  c.soA = (size_t)(c.w * 32 + srow) * D_ + sslot * 8;
  return c;
}

// stage one 256x32 plane (BK=32): wave w covers rows [w*32, w*32+32), 2 gl_lds
__device__ __forceinline__ void stage_plane(const ushort* src, ushort* dstbase,
                                            const CoreCtx& c, int k0) {
  const size_t a0 = c.soA + k0, a1 = a0 + (size_t)16 * D_;
  ushort* d0 = dstbase + c.w * 1024;
  gl_lds16(src + a0, d0);
  gl_lds16(src + a1, d0 + 512);
}

#define VMCNT(n) asm volatile("s_waitcnt vmcnt(" #n ")" ::: "memory")
#define BARRIER() do { asm volatile("" ::: "memory"); \
                       __builtin_amdgcn_s_barrier();  \
                       asm volatile("" ::: "memory"); } while (0)

// --- gemm1 core: 3 planes (Ah | Bh | Bl), BK=32, 2-phase counted-vmcnt (r8-proven) ---
__device__ __forceinline__ void core_loop3(const CoreCtx& c,
    const ushort* Ah, const ushort* Bh, const ushort* Bl,
    ushort* lbuf, f32x4 acc[8][4])
{
  stage_plane(Ah, lbuf,         c, 0);
  stage_plane(Bh, lbuf + 8192,  c, 0);
  stage_plane(Bl, lbuf + 16384, c, 0);

  for (int t = 0; t < 32; ++t) {
    const ushort* cb = lbuf + (t & 1) * 24576;
    ushort* nb = lbuf + ((t + 1) & 1) * 24576;
    const int kn = (t + 1) * 32;
    const bool pf = (t < 31);
    f16x8 a[8], bh4[4], bl4[4];

    // ---- phase 1: hh ----
    VMCNT(2);                       // Ah,Bh(t) landed; Bl(t) may fly
    BARRIER();
#pragma unroll
    for (int n = 0; n < 4; ++n) {
      const int r = c.wn * 64 + n * 16 + c.ln;
      bh4[n] = *(const f16x8*)&cb[8192 + r * 32 + c.ko];
    }
#pragma unroll
    for (int m = 0; m < 8; ++m) {
      const int r = c.wm * 128 + m * 16 + c.ln;
      a[m] = *(const f16x8*)&cb[r * 32 + c.ko];
    }
    if (pf) { stage_plane(Ah, nb, c, kn); stage_plane(Bh, nb + 8192, c, kn); }
    __builtin_amdgcn_s_setprio(1);
#pragma unroll
    for (int m = 0; m < 8; ++m)
#pragma unroll
      for (int n = 0; n < 4; ++n)
        acc[m][n] = __builtin_amdgcn_mfma_f32_16x16x32_f16(a[m], bh4[n], acc[m][n], 0, 0, 0);
    __builtin_amdgcn_s_setprio(0);

    // ---- phase 2: A_hi x B_lo ----
    if (pf) { VMCNT(4); } else { VMCNT(0); }   // Bl(t) landed
    BARRIER();
#pragma unroll
    for (int n = 0; n < 4; ++n) {
      const int r = c.wn * 64 + n * 16 + c.ln;
      bl4[n] = *(const f16x8*)&cb[16384 + r * 32 + c.ko];
    }
    if (pf) stage_plane(Bl, nb + 16384, c, kn);
    __builtin_amdgcn_s_setprio(1);
#pragma unroll
    for (int m = 0; m < 8; ++m)
#pragma unroll
      for (int n = 0; n < 4; ++n)
        acc[m][n] = __builtin_amdgcn_mfma_f32_16x16x32_f16(a[m], bl4[n], acc[m][n], 0, 0, 0);
    __builtin_amdgcn_s_setprio(0);
  }
}

// ---------- GEMM1: Y = (x1 @ (U*2048)) / 2048 -> f16 hi plane ----------
__global__ __launch_bounds__(512, 2) void gemm1_k(
    const ushort* __restrict__ x1h,
    const ushort* __restrict__ UTh, const ushort* __restrict__ UTl,
    ushort* __restrict__ Yh)
{
  __shared__ __attribute__((aligned(16))) ushort lbuf[65536];
  const int z = blockIdx.z;
  const int orig = blockIdx.x;                 // 0..31
  const int xc = orig & 7, j = orig >> 3;      // j 0..3
  const int bx = (xc & 3) * 2 + (j & 1);       // 0..7
  const int by = (xc >> 2) * 2 + (j >> 1);     // 0..3

  const size_t zb = (size_t)z * (L_ * D_);
  const ushort* Ah = x1h + zb + (size_t)bx * 256 * D_;
  const ushort* Bh = UTh + (size_t)by * 256 * D_;
  const ushort* Bl = UTl + (size_t)by * 256 * D_;

  CoreCtx c = make_ctx();
  f32x4 acc[8][4];
#pragma unroll
  for (int m = 0; m < 8; ++m)
#pragma unroll
    for (int n = 0; n < 4; ++n) acc[m][n] = (f32x4){0.f, 0.f, 0.f, 0.f};

  core_loop3(c, Ah, Bh, Bl, lbuf, acc);

  __syncthreads();   // lbuf reused below

  // epilogue: unscale by 2^-11, convert to f16, LDS-coalesce, write Yh.
  ushort* ep = lbuf + c.w * 8192;
  const int grow = bx * 256 + c.wm * 128;
  const int gcol = by * 256 + c.wn * 64;
#pragma unroll
  for (int m = 0; m < 8; ++m)
#pragma unroll
    for (int n = 0; n < 4; ++n)
#pragma unroll
      for (int r2 = 0; r2 < 4; ++r2) {
        float v = acc[m][n][r2] * 4.8828125e-4f;   // 1/2048
        ep[(m * 16 + c.kq * 4 + r2) * 64 + n * 16 + c.ln] = f16_bits(v);
      }
#pragma unroll
  for (int q = 0; q < 16; ++q) {
    const int chunk = q * 64 + c.lane;
    const int row = chunk >> 3, c8 = (chunk & 7) * 8;
    f16x8 v = *(const f16x8*)&ep[row * 64 + c8];
    *(f16x8*)&Yh[zb + (size_t)(grow + row) * D_ + gcol + c8] = v;
  }
}

// ---------- GEMM2: M = Yh @ x2h^T, BK=64, faithful m201 4-phase template ----------
// LDS: 2 buffers x (A[256][64] | B[256][64]) = 128KB. Rows of 64 ushorts =
// 8 x 16B slots; swizzle phys_slot = slot ^ (row&7), applied on the GLOBAL
// source at stage time and on the ds_read address (r11/r13-verified).
//
// Per tile t, 4 phases; each phase:
//   { ds_read frags | issue 1 half-tile stage (2 gl_lds) | counted vmcnt |
//     barrier | setprio(1) 16 MFMA setprio(0) | barrier }
// Stage order (tile t stages tile t+1): ph0->A0', ph1->B0', ph2->B1', ph3->A1'.
// Consumption (tile t): ph0 reads A0,B0; ph1 reads B1; ph2 reads A1; ph3 none.
// vmcnt(4) at ph0/ph1/ph3; >=4 loads always in flight mid-loop (T4).
__global__ __launch_bounds__(512, 2) void gemm2_k(
    const ushort* __restrict__ Yh,
    const ushort* __restrict__ x2h,
    unsigned* __restrict__ rmxg, unsigned* __restrict__ cmxg)
{
  __shared__ __attribute__((aligned(16))) ushort lbuf[65536];  // 2 x 32768
  const int z = blockIdx.z;
  const int orig = blockIdx.x;                 // 0..63
  const int xc = orig & 7, j = orig >> 3;      // j 0..7
  const int bx = (xc & 3) * 2 + (j & 1);       // 0..7
  const int by = (xc >> 2) * 4 + (j >> 1);     // 0..7

  const size_t zb = (size_t)z * (L_ * D_);
  const ushort* Ap = Yh + zb + (size_t)bx * 256 * D_;
  const ushort* Bp = x2h + zb + (size_t)by * 256 * D_;

  const int tid = threadIdx.x;
  const int w = tid >> 6, lane = tid & 63;
  const int ln = lane & 15, kq = lane >> 4;
  const int wm = w >> 2, wn = w & 3;
  const int ko0 = ((kq)     ^ (ln & 7)) * 8;   // ks=0 slot (swizzled), ushorts
  const int ko1 = ((4 + kq) ^ (ln & 7)) * 8;   // ks=1
  const int srh = lane >> 3;                   // 0..7
  const int ssl = (lane & 7) ^ srh;            // swizzled source slot
  const int rA0 = (w >> 2) * 128 + (w & 3) * 16;  // per-wave A row base (stage)
  const int rB0 = (w >> 1) * 64 + (w & 1) * 16;   // per-wave B row base (stage)

  f32x4 acc[8][4];
#pragma unroll
  for (int m = 0; m < 8; ++m)
#pragma unroll
    for (int n = 0; n < 4; ++n) acc[m][n] = (f32x4){0.f, 0.f, 0.f, 0.f};

// kt = TILE INDEX (k element offset = kt*64)
#define STG(nbuf, plofs, srcp, rowbase, kt) do {                                     \
    const size_t a_ = (size_t)((rowbase) + srh) * D_ + (size_t)(kt) * 64 + ssl * 8;  \
    ushort* d_ = (nbuf) + (plofs) + (rowbase) * 64;                                  \
    gl_lds16((srcp) + a_, d_);                                                       \
    gl_lds16((srcp) + a_ + (size_t)8 * D_, d_ + 512);                                \
  } while (0)

  // prologue: tile 0's 4 halves in consumption order A0,B0,B1,A1
  STG(lbuf, 0,     Ap, rA0,      0);
  STG(lbuf, 16384, Bp, rB0,      0);
  STG(lbuf, 16384, Bp, rB0 + 32, 0);
  STG(lbuf, 0,     Ap, rA0 + 64, 0);
  VMCNT(4);            // A0(0),B0(0) landed; B1(0),A1(0) in flight
  BARRIER();

  f16x8 a[4][2], b0[2][2], b1[2][2];

  for (int t = 0; t < 16; ++t) {
    const ushort* cb = lbuf + (t & 1) * 32768;
    ushort* nb = lbuf + ((t + 1) & 1) * 32768;
    const bool pf = (t < 15);
    const int kn = t + 1;                      // FIXED: tile index, not element offset
    const ushort* aP = cb;
    const ushort* bP = cb + 16384;

    // ===== phase 0: m0-3 x n0-1 (reads A-half0 + B-half0) =====
#pragma unroll
    for (int ks = 0; ks < 2; ++ks) {
      const int ko = ks ? ko1 : ko0;
#pragma unroll
      for (int nt = 0; nt < 2; ++nt)
        b0[nt][ks] = *(const f16x8*)&bP[(wn * 64 + nt * 16 + ln) * 64 + ko];
#pragma unroll
      for (int m = 0; m < 4; ++m)
        a[m][ks] = *(const f16x8*)&aP[(wm * 128 + m * 16 + ln) * 64 + ko];
    }
    if (pf) STG(nb, 0, Ap, rA0, kn);
    if (pf) { VMCNT(4); } else { VMCNT(2); }   // publish B1(t)
    BARRIER();
    __builtin_amdgcn_s_setprio(1);
#pragma unroll
    for (int ks = 0; ks < 2; ++ks)
#pragma unroll
      for (int m = 0; m < 4; ++m)
#pragma unroll
        for (int nt = 0; nt < 2; ++nt)
          acc[m][nt] = __builtin_amdgcn_mfma_f32_16x16x32_f16(a[m][ks], b0[nt][ks], acc[m][nt], 0, 0, 0);
    __builtin_amdgcn_s_setprio(0);
    BARRIER();

    // ===== phase 1: m0-3 x n2-3 (reads B-half1) =====
#pragma unroll
    for (int ks = 0; ks < 2; ++ks) {
      const int ko = ks ? ko1 : ko0;
#pragma unroll
      for (int nt = 0; nt < 2; ++nt)
        b1[nt][ks] = *(const f16x8*)&bP[(wn * 64 + (2 + nt) * 16 + ln) * 64 + ko];
    }
    if (pf) STG(nb, 16384, Bp, rB0, kn);
    if (pf) { VMCNT(4); } else { VMCNT(0); }   // publish A1(t)
    BARRIER();
    __builtin_amdgcn_s_setprio(1);
#pragma unroll
    for (int ks = 0; ks < 2; ++ks)
#pragma unroll
      for (int m = 0; m < 4; ++m)
#pragma unroll
        for (int nt = 0; nt < 2; ++nt)
          acc[m][2 + nt] = __builtin_amdgcn_mfma_f32_16x16x32_f16(a[m][ks], b1[nt][ks], acc[m][2 + nt], 0, 0, 0);
    __builtin_amdgcn_s_setprio(0);
    BARRIER();

    // ===== phase 2: m4-7 x n0-1 (reads A-half1; overwrites a[][]) =====
#pragma unroll
    for (int ks = 0; ks < 2; ++ks) {
      const int ko = ks ? ko1 : ko0;
#pragma unroll
      for (int m = 0; m < 4; ++m)
        a[m][ks] = *(const f16x8*)&aP[(wm * 128 + (4 + m) * 16 + ln) * 64 + ko];
    }
    if (pf) STG(nb, 16384, Bp, rB0 + 32, kn);
    BARRIER();                                  // no vmcnt: ph3 reads nothing
    __builtin_amdgcn_s_setprio(1);
#pragma unroll
    for (int ks = 0; ks < 2; ++ks)
#pragma unroll
      for (int m = 0; m < 4; ++m)
#pragma unroll
        for (int nt = 0; nt < 2; ++nt)
          acc[4 + m][nt] = __builtin_amdgcn_mfma_f32_16x16x32_f16(a[m][ks], b0[nt][ks], acc[4 + m][nt], 0, 0, 0);
    __builtin_amdgcn_s_setprio(0);
    BARRIER();

    // ===== phase 3: m4-7 x n2-3 (no reads) =====
    if (pf) STG(nb, 0, Ap, rA0 + 64, kn);
    if (pf) { VMCNT(4); }                       // publish A0(t+1),B0(t+1)
    BARRIER();
    __builtin_amdgcn_s_setprio(1);
#pragma unroll
    for (int ks = 0; ks < 2; ++ks)
#pragma unroll
      for (int m = 0; m < 4; ++m)
#pragma unroll
        for (int nt = 0; nt < 2; ++nt)
          acc[4 + m][2 + nt] = __builtin_amdgcn_mfma_f32_16x16x32_f16(a[m][ks], b1[nt][ks], acc[4 + m][2 + nt], 0, 0, 0);
    __builtin_amdgcn_s_setprio(0);
    BARRIER();
  }
#undef STG

  // epilogue: tile row/col max -> LDS atomics -> global atomics
  __syncthreads();
  unsigned* red = (unsigned*)lbuf;   // [0..255]=row max, [256..511]=col max
  red[tid] = 0u;
  __syncthreads();

#pragma unroll
  for (int m = 0; m < 8; ++m) {
#pragma unroll
    for (int r2 = 0; r2 < 4; ++r2) {
      float v = fmaxf(fmaxf(acc[m][0][r2], acc[m][1][r2]),
                      fmaxf(acc[m][2][r2], acc[m][3][r2]));
#pragma unroll
      for (int s = 1; s < 16; s <<= 1) v = fmaxf(v, __shfl_xor(v, s));
      if (ln == 0) atomicMax(&red[wm * 128 + m * 16 + kq * 4 + r2], enc_f(v));
    }
  }
#pragma unroll
  for (int n = 0; n < 4; ++n) {
    float v = -3.4e38f;
#pragma unroll
    for (int m = 0; m < 8; ++m)
#pragma unroll
      for (int r2 = 0; r2 < 4; ++r2) v = fmaxf(v, acc[m][n][r2]);
    v = fmaxf(v, __shfl_xor(v, 16));
    v = fmaxf(v, __shfl_xor(v, 32));
    if (kq == 0) atomicMax(&red[256 + wn * 64 + n * 16 + ln], enc_f(v));
  }
  __syncthreads();
  if (tid < 256) atomicMax(&rmxg[(size_t)z * L_ + bx * 256 + tid], red[tid]);
  else           atomicMax(&cmxg[(size_t)z * L_ + by * 256 + (tid - 256)], red[tid]);
}

// ---------- softmax over 2048 encoded maxima per batch ----------
__global__ void softmax_k(const unsigned* __restrict__ enc, float* __restrict__ w) {
  __shared__ float red[256];
  const int b = blockIdx.x, tid = threadIdx.x;
  const unsigned* e = enc + (size_t)b * L_;
  float* wb = w + (size_t)b * L_;
  float vals[8];
  float lmax = -3.4e38f;
#pragma unroll
  for (int q = 0; q < 8; ++q) {
    float f = dec_f(e[q * 256 + tid]);
    vals[q] = f;
    lmax = fmaxf(lmax, f);
  }
  red[tid] = lmax; __syncthreads();
  for (int s = 128; s > 0; s >>= 1) {
    if (tid < s) red[tid] = fmaxf(red[tid], red[tid + s]);
    __syncthreads();
  }
  const float mx = red[0];
  __syncthreads();
  float lsum = 0.f;
#pragma unroll
  for (int q = 0; q < 8; ++q) { vals[q] = expf(vals[q] - mx); lsum += vals[q]; }
  red[tid] = lsum; __syncthreads();
  for (int s = 128; s > 0; s >>= 1) {
    if (tid < s) red[tid] += red[tid + s];
    __syncthreads();
  }
  const float inv = 1.f / red[0];
#pragma unroll
  for (int q = 0; q < 8; ++q) wb[q * 256 + tid] = vals[q] * inv;
}

// ---------- weighted sum (f16 input planes) ----------
__global__ void wsum_k(const float* __restrict__ w, const ushort* __restrict__ xh,
                       float* __restrict__ out) {
  __shared__ float ws[256];
  const int tid = threadIdx.x;
  const int b = blockIdx.y;
  const int i0 = blockIdx.x * 256;
  ws[tid] = w[(size_t)b * L_ + i0 + tid];
  __syncthreads();
  const int d0 = tid * 4;
  const ushort* xb = xh + ((size_t)b * L_ + i0) * D_ + d0;
  float4 acc = {0.f, 0.f, 0.f, 0.f};
  for (int i = 0; i < 256; ++i) {
    ushort4 v = *(const ushort4*)(xb + (size_t)i * D_);
    float wi = ws[i];
    acc.x = fmaf(wi, (float)__builtin_bit_cast(_Float16, v.x), acc.x);
    acc.y = fmaf(wi, (float)__builtin_bit_cast(_Float16, v.y), acc.y);
    acc.z = fmaf(wi, (float)__builtin_bit_cast(_Float16, v.z), acc.z);
    acc.w = fmaf(wi, (float)__builtin_bit_cast(_Float16, v.w), acc.w);
  }
  float* o = out + (size_t)b * D_ + d0;
  atomicAdd(o + 0, acc.x);
  atomicAdd(o + 1, acc.y);
  atomicAdd(o + 2, acc.z);
  atomicAdd(o + 3, acc.w);
}

extern "C" void kernel_launch(void* const* d_in, const int* in_sizes, int n_in,
                              void* d_out, int out_size, void* d_ws, size_t ws_size,
                              hipStream_t stream) {
  (void)in_sizes; (void)n_in; (void)out_size;
  const float* x1 = (const float*)d_in[0];
  const float* x2 = (const float*)d_in[1];
  const float* U  = (const float*)d_in[2];
  float* out = (float*)d_out;

  // workspace layout
  char* p = (char*)d_ws;
  ushort* UTh = (ushort*)p; p += (size_t)D_ * D_ * 2;
  ushort* UTl = (ushort*)p; p += (size_t)D_ * D_ * 2;
  unsigned* rowmax = (unsigned*)p; p += (size_t)B_ * L_ * 4;
  unsigned* colmax = (unsigned*)p; p += (size_t)B_ * L_ * 4;
  float* w1 = (float*)p; p += (size_t)B_ * L_ * 4;
  float* w2 = (float*)p; p += (size_t)B_ * L_ * 4;
  const size_t fixed = (size_t)(p - (char*)d_ws);
  const size_t perB = (size_t)3 * L_ * D_ * 2;    // 3 f16 planes per batch = 12MB
  int G = 1;
  if (ws_size > fixed) {
    size_t g = (ws_size - fixed) / perB;
    G = g < 1 ? 1 : (g > (size_t)B_ ? B_ : (int)g);
  }
  ushort* x1h = (ushort*)p;
  ushort* x2h = x1h + (size_t)G * L_ * D_;
  ushort* Yh  = x2h + (size_t)G * L_ * D_;

  hipMemsetAsync(d_out, 0, (size_t)2 * B_ * D_ * 4, stream);
  hipMemsetAsync(rowmax, 0, (size_t)2 * B_ * L_ * 4, stream); // rowmax+colmax contiguous

  transdec_k<<<dim3(32, 32), dim3(32, 8), 0, stream>>>(U, UTh, UTl);

  for (int g0 = 0; g0 < B_; g0 += G) {
    const int Gc = (B_ - g0) < G ? (B_ - g0) : G;
    const int n4 = Gc * (L_ * D_ / 4);
    dec1_k<<<dim3(1024), 256, 0, stream>>>(
        (const float4*)(x1 + (size_t)g0 * L_ * D_), (uint2*)x1h, n4);
    dec1_k<<<dim3(1024), 256, 0, stream>>>(
        (const float4*)(x2 + (size_t)g0 * L_ * D_), (uint2*)x2h, n4);
    gemm1_k<<<dim3(32, 1, Gc), 512, 0, stream>>>(x1h, UTh, UTl, Yh);
    gemm2_k<<<dim3(64, 1, Gc), 512, 0, stream>>>(Yh, x2h,
        rowmax + (size_t)g0 * L_, colmax + (size_t)g0 * L_);
    // per-group softmax + weighted sums (f16 planes are group-local)
    softmax_k<<<dim3(Gc), 256, 0, stream>>>(rowmax + (size_t)g0 * L_,
                                            w1 + (size_t)g0 * L_);
    softmax_k<<<dim3(Gc), 256, 0, stream>>>(colmax + (size_t)g0 * L_,
                                            w2 + (size_t)g0 * L_);
    wsum_k<<<dim3(8, Gc), 256, 0, stream>>>(w1 + (size_t)g0 * L_, x1h,
                                            out + (size_t)g0 * D_);
    wsum_k<<<dim3(8, Gc), 256, 0, stream>>>(w2 + (size_t)g0 * L_, x2h,
                                            out + (size_t)(B_ + g0) * D_);
  }
}